// Round 9
// baseline (202.509 us; speedup 1.0000x reference)
//
#include <hip/hip_runtime.h>
#include <stdint.h>

typedef __attribute__((ext_vector_type(4))) float f32x4;
typedef __attribute__((ext_vector_type(8))) __bf16 bf16x8;
typedef __attribute__((ext_vector_type(4))) unsigned int u32x4;
typedef unsigned short u16;

#define B_DIM 2
#define T_DIM 2048
#define C_DIM 2048
#define H_Q   16
#define H_KV  4
#define HD    128
#define NQKV  3072            // 2048 q | 512 k | 512 v
#define MTOK  4096            // B*T
#define RMS_EPS 1.1920928955078125e-07f
// 1/sqrt(128) * log2(e), folded into q's rms scale so S comes out in exp2 domain
#define Q_SCALE 0.12751749f

__device__ __forceinline__ u16 f2bf(float f) {
  union { float f; unsigned int u; } v; v.f = f;
  unsigned int r = v.u + 0x7FFFu + ((v.u >> 16) & 1u);   // RNE
  return (u16)(r >> 16);
}
__device__ __forceinline__ float bf2f(u16 h) {
  union { unsigned int u; float f; } v; v.u = ((unsigned int)h) << 16;
  return v.f;
}
__device__ __forceinline__ f32x4 mfma16(bf16x8 a, bf16x8 b, f32x4 c) {
  return __builtin_amdgcn_mfma_f32_16x16x32_bf16(a, b, c, 0, 0, 0);
}
// async global->LDS, 16B per lane; lds base must be wave-uniform (HW: base + lane*16)
__device__ __forceinline__ void gl_lds16(const void* g, void* l) {
  __builtin_amdgcn_global_load_lds(
      (const __attribute__((address_space(1))) unsigned int*)g,
      (__attribute__((address_space(3))) unsigned int*)l, 16, 0, 0);
}

// ---------------- prep: weight transposes (blocks 0..2559) + x cast (rest) ----------------
__global__ __launch_bounds__(256) void prep_kernel(const float* __restrict__ x,
                                                   const float* __restrict__ wq,
                                                   const float* __restrict__ wk,
                                                   const float* __restrict__ wv,
                                                   const float* __restrict__ wo,
                                                   u16* __restrict__ xb,
                                                   u16* __restrict__ wqkvb,
                                                   u16* __restrict__ wob) {
  __shared__ float tile[64][65];
  int bid = blockIdx.x, t = threadIdx.x;
  if (bid < 2560) {                       // transpose+cast fp32 [K][N] -> bf16 [N][2048]
    int nb = bid % 80, kb = bid / 80;
    const float* src; u16* dst; int srcN, nloc;
    if (nb < 32)      { src = wq; srcN = 2048; nloc = nb;      dst = wqkvb; }
    else if (nb < 40) { src = wk; srcN = 512;  nloc = nb - 32; dst = wqkvb + (size_t)2048 * 2048; }
    else if (nb < 48) { src = wv; srcN = 512;  nloc = nb - 40; dst = wqkvb + (size_t)2560 * 2048; }
    else              { src = wo; srcN = 2048; nloc = nb - 48; dst = wob; }
    int n0 = nloc * 64, k0 = kb * 64;
    #pragma unroll
    for (int idx = t; idx < 4096; idx += 256) {
      int r = idx >> 6, c = idx & 63;
      tile[r][c] = src[(size_t)(k0 + r) * srcN + n0 + c];
    }
    __syncthreads();
    #pragma unroll
    for (int idx = t; idx < 4096; idx += 256) {
      int r = idx >> 6, c = idx & 63;
      dst[(size_t)(n0 + r) * 2048 + k0 + c] = f2bf(tile[c][r]);
    }
  } else {                                // cast x
    int i = ((bid - 2560) * 256 + t) * 4;
    if (i >= MTOK * C_DIM) return;
    float4 v = *(const float4*)(x + i);
    u16 o0 = f2bf(v.x), o1 = f2bf(v.y), o2 = f2bf(v.z), o3 = f2bf(v.w);
    unsigned int lo = (unsigned int)o0 | ((unsigned int)o1 << 16);
    unsigned int hi = (unsigned int)o2 | ((unsigned int)o3 << 16);
    *(uint2*)(xb + i) = make_uint2(lo, hi);
  }
}

// ---------------- rope+rms (in place on q,k) + V^T precompute, one dispatch ----------------
__global__ __launch_bounds__(256) void ropevt_kernel(u16* __restrict__ qkv,
                                                     const float* __restrict__ cosb,
                                                     const float* __restrict__ sinb,
                                                     u16* __restrict__ vt) {
  __shared__ __align__(16) u16 tile[64][136];
  int bid = blockIdx.x, tid = threadIdx.x;
  if (bid < 256) {                        // vtrans: qkv v-section -> vt[b][kvh][d][T]
    int tt0 = (bid & 31) * 64;
    int kvh = (bid >> 5) & 3;
    int b   = bid >> 7;
    const u16* vp = qkv + ((size_t)b * T_DIM + tt0) * NQKV + C_DIM + H_KV * HD + kvh * HD;
    #pragma unroll
    for (int i = 0; i < 4; ++i) {
      int cid = tid + i * 256;
      int r = cid >> 4, c = cid & 15;
      u32x4 v = *(const u32x4*)(vp + (size_t)r * NQKV + c * 8);
      *(u32x4*)&tile[r][c * 8] = v;
    }
    __syncthreads();
    u16* op = vt + ((size_t)(b * H_KV + kvh) * HD) * T_DIM + tt0;
    #pragma unroll
    for (int i = 0; i < 4; ++i) {
      int cid = tid + i * 256;
      int d = cid >> 3, tc = cid & 7;
      u16 vals[8];
      #pragma unroll
      for (int j = 0; j < 8; ++j) vals[j] = tile[tc * 8 + j][d];
      u32x4 w;
      w.x = (unsigned int)vals[0] | ((unsigned int)vals[1] << 16);
      w.y = (unsigned int)vals[2] | ((unsigned int)vals[3] << 16);
      w.z = (unsigned int)vals[4] | ((unsigned int)vals[5] << 16);
      w.w = (unsigned int)vals[6] | ((unsigned int)vals[7] << 16);
      *(u32x4*)(op + (size_t)d * T_DIM + tc * 8) = w;
    }
  } else {                                // rope+rms: one wave per (token, head)
    int gw = ((bid - 256) * 256 + tid) >> 6;
    int lane = tid & 63;
    int hh = gw % (H_Q + H_KV);
    int tok = gw / (H_Q + H_KV);
    int t = tok & (T_DIM - 1);
    bool isq = (hh < H_Q);
    int base = isq ? hh * HD : (C_DIM + (hh - H_Q) * HD);
    u16* p = qkv + (size_t)tok * NQKV + base;
    float x1 = bf2f(p[lane]);
    float x2 = bf2f(p[lane + 64]);
    float c = cosb[t * 64 + lane];
    float s = sinb[t * 64 + lane];
    float o1 =  x1 * c + x2 * s;
    float o2 = -x1 * s + x2 * c;
    float ss = o1 * o1 + o2 * o2;
    #pragma unroll
    for (int off = 1; off < 64; off <<= 1) ss += __shfl_xor(ss, off);
    float r = rsqrtf(ss * (1.0f / 128.0f) + RMS_EPS);
    if (isq) r *= Q_SCALE;
    p[lane]      = f2bf(o1 * r);
    p[lane + 64] = f2bf(o2 * r);
  }
}

// ---------------- 256x256 8-wave FINE 8-phase GEMM (m201-style, race-free 2-dbuf) ----------
// C[M][N] = A[M][K]*Bt[N][K]^T. BK=64 (2 kslices). 8 waves 2Mx4N, per-wave 128x64 out.
// LDS fragment-major: [dbuf][op][ks][rb*512 + lane*8]; frag read = base+lane*16 (no swz).
// Per K-tile, 4 phases: {stage ONE half-tile of t+1 into the OTHER dbuf (2 gl_lds) |
// 4-8 ds_read | barrier | lgkmcnt(0) | setprio 16 MFMA | [vmcnt(2)] | barrier}.
// Half order B0,B1,A0,A1 with A-halves = frag-groups {0-3,8-11}/{4-7,12-15}: the
// last-staged half (A1) is first consumed at ph1, guarded by ph0-end vmcnt(2).
// In-flight oscillates 2<->8 per wave; never drains in-loop (T4).
template<int BF16OUT>
__global__ __launch_bounds__(512) void gemm256_kernel(const u16* __restrict__ A,
                                                      const u16* __restrict__ Bt,
                                                      void* __restrict__ Cv,
                                                      int M, int N, int K) {
  __shared__ __align__(16) u16 L[2][2][2][8192];   // [dbuf][A=0/B=1][ks][rb*512+lane*8]
  const int tid = threadIdx.x, lane = tid & 63, wid = tid >> 6;
  const int l15 = lane & 15, l4 = lane >> 4;
  const int nbn = N >> 8;
  const int nwg = gridDim.x;
  const int cpx = nwg >> 3;                        // nwg % 8 == 0 for our shapes
  const int swz = (blockIdx.x & 7) * cpx + (blockIdx.x >> 3);
  const int m0 = (swz / nbn) << 8, n0 = (swz % nbn) << 8;
  const int wm = (wid >> 2) << 7, wn = (wid & 3) << 6;
  const int rbA = wm >> 4, rbB = wn >> 4;
  const int NT = K >> 6;

  const u16* Ag = A  + (size_t)(m0 + l15) * K + l4 * 8;
  const u16* Bg = Bt + (size_t)(n0 + l15) * K + l4 * 8;

  f32x4 acc[8][4] = {};

  // type: 0 = B rb 0-7 | 1 = B rb 8-15 | 2 = A rb {0-3,8-11} | 3 = A rb {4-7,12-15}
  auto stage = [&](int tsrc, int buf, int type) {
    int op = (type < 2) ? 1 : 0;
    int rb;
    if      (type == 0) rb = wid;
    else if (type == 1) rb = 8 + wid;
    else if (type == 2) rb = (wid & 3) + ((wid >> 2) << 3);
    else                rb = 4 + (wid & 3) + ((wid >> 2) << 3);
    const u16* src = (op ? Bg : Ag) + (size_t)rb * 16 * K + (size_t)tsrc * 64;
    gl_lds16(src,      &L[buf][op][0][rb * 512]);
    gl_lds16(src + 32, &L[buf][op][1][rb * 512]);
  };

  // prologue: stage tile 0; retire all but A1 (A1 lands under ph0's compute)
  stage(0, 0, 0); stage(0, 0, 1); stage(0, 0, 2); stage(0, 0, 3);
  asm volatile("s_waitcnt vmcnt(2)" ::: "memory");
  __builtin_amdgcn_s_barrier();

  for (int t = 0; t < NT; ++t) {
    const int cur = t & 1, nxt = cur ^ 1;
    const int ts = (t + 1 < NT) ? (t + 1) : t;     // dup-stage into dead buffer at tail
    bf16x8 a[4], b0[4], b1[4];

    // ---- ph0: ks0, m-frags 0-3 (+ B ks0) ----
    stage(ts, nxt, 0);
    #pragma unroll
    for (int nf = 0; nf < 4; ++nf)
      b0[nf] = __builtin_bit_cast(bf16x8, *(const u32x4*)&L[cur][1][0][(rbB + nf) * 512 + lane * 8]);
    #pragma unroll
    for (int i = 0; i < 4; ++i)
      a[i] = __builtin_bit_cast(bf16x8, *(const u32x4*)&L[cur][0][0][(rbA + i) * 512 + lane * 8]);
    __builtin_amdgcn_s_barrier();
    asm volatile("s_waitcnt lgkmcnt(0)" ::: "memory");
    __builtin_amdgcn_s_setprio(1);
    #pragma unroll
    for (int mf = 0; mf < 4; ++mf)
      #pragma unroll
      for (int nf = 0; nf < 4; ++nf)
        acc[mf][nf] = mfma16(a[mf], b0[nf], acc[mf][nf]);
    __builtin_amdgcn_s_setprio(0);
    asm volatile("s_waitcnt vmcnt(2)" ::: "memory");   // retire A1(t); B0(t+1) stays out
    __builtin_amdgcn_s_barrier();

    // ---- ph1: ks0, m-frags 4-7 ----
    stage(ts, nxt, 1);
    #pragma unroll
    for (int i = 0; i < 4; ++i)
      a[i] = __builtin_bit_cast(bf16x8, *(const u32x4*)&L[cur][0][0][(rbA + 4 + i) * 512 + lane * 8]);
    __builtin_amdgcn_s_barrier();
    asm volatile("s_waitcnt lgkmcnt(0)" ::: "memory");
    __builtin_amdgcn_s_setprio(1);
    #pragma unroll
    for (int mf = 0; mf < 4; ++mf)
      #pragma unroll
      for (int nf = 0; nf < 4; ++nf)
        acc[4 + mf][nf] = mfma16(a[mf], b0[nf], acc[4 + mf][nf]);
    __builtin_amdgcn_s_setprio(0);
    __builtin_amdgcn_s_barrier();

    // ---- ph2: ks1, m-frags 0-3 (+ B ks1) ----
    stage(ts, nxt, 2);
    #pragma unroll
    for (int nf = 0; nf < 4; ++nf)
      b1[nf] = __builtin_bit_cast(bf16x8, *(const u32x4*)&L[cur][1][1][(rbB + nf) * 512 + lane * 8]);
    #pragma unroll
    for (int i = 0; i < 4; ++i)
      a[i] = __builtin_bit_cast(bf16x8, *(const u32x4*)&L[cur][0][1][(rbA + i) * 512 + lane * 8]);
    __builtin_amdgcn_s_barrier();
    asm volatile("s_waitcnt lgkmcnt(0)" ::: "memory");
    __builtin_amdgcn_s_setprio(1);
    #pragma unroll
    for (int mf = 0; mf < 4; ++mf)
      #pragma unroll
      for (int nf = 0; nf < 4; ++nf)
        acc[mf][nf] = mfma16(a[mf], b1[nf], acc[mf][nf]);
    __builtin_amdgcn_s_setprio(0);
    __builtin_amdgcn_s_barrier();

    // ---- ph3: ks1, m-frags 4-7 ----
    stage(ts, nxt, 3);
    #pragma unroll
    for (int i = 0; i < 4; ++i)
      a[i] = __builtin_bit_cast(bf16x8, *(const u32x4*)&L[cur][0][1][(rbA + 4 + i) * 512 + lane * 8]);
    __builtin_amdgcn_s_barrier();
    asm volatile("s_waitcnt lgkmcnt(0)" ::: "memory");
    __builtin_amdgcn_s_setprio(1);
    #pragma unroll
    for (int mf = 0; mf < 4; ++mf)
      #pragma unroll
      for (int nf = 0; nf < 4; ++nf)
        acc[4 + mf][nf] = mfma16(a[mf], b1[nf], acc[4 + mf][nf]);
    __builtin_amdgcn_s_setprio(0);
    asm volatile("s_waitcnt vmcnt(2)" ::: "memory");   // retire B0,B1,A0 of t+1
    __builtin_amdgcn_s_barrier();
  }
  asm volatile("s_waitcnt vmcnt(0)" ::: "memory");     // drain dup stages

  #pragma unroll
  for (int mf = 0; mf < 8; ++mf)
    #pragma unroll
    for (int nf = 0; nf < 4; ++nf)
      #pragma unroll
      for (int reg = 0; reg < 4; ++reg) {
        int row = m0 + wm + mf * 16 + l4 * 4 + reg;
        int col = n0 + wn + nf * 16 + l15;
        float v = acc[mf][nf][reg];
        if (BF16OUT) ((u16*)Cv)[(size_t)row * N + col] = f2bf(v);
        else         ((float*)Cv)[(size_t)row * N + col] = v;
      }
}

// ---------------- bf16 GEMM: C[M][N] = A[M][K] * Bt[N][K]^T (128^2, out proj) ----------------
template<int BF16OUT>
__global__ __launch_bounds__(256) void gemm_bt_kernel(const u16* __restrict__ A,
                                                      const u16* __restrict__ Bt,
                                                      void* __restrict__ Cv,
                                                      int M, int N, int K) {
  __shared__ __align__(16) u16 Asm[128 * 64];
  __shared__ __align__(16) u16 Bsm[128 * 64];
  const int tid = threadIdx.x;
  const int lane = tid & 63;
  const int wid = tid >> 6;
  const int m0 = blockIdx.y * 128, n0 = blockIdx.x * 128;
  const int wm = (wid >> 1) * 64, wn = (wid & 1) * 64;
  const int l15 = lane & 15, l4 = lane >> 4;
  const int csrc = (lane & 7) ^ (lane >> 3);      // pre-swizzled source chunk
  f32x4 acc[4][4] = {};

  for (int k0 = 0; k0 < K; k0 += 64) {
    __syncthreads();
    #pragma unroll
    for (int i = 0; i < 4; ++i) {
      int g = wid * 4 + i;
      int row = g * 8 + (lane >> 3);
      gl_lds16(A  + (size_t)(m0 + row) * K + k0 + csrc * 8, (char*)Asm + g * 1024);
      gl_lds16(Bt + (size_t)(n0 + row) * K + k0 + csrc * 8, (char*)Bsm + g * 1024);
    }
    __syncthreads();
    #pragma unroll
    for (int ks = 0; ks < 2; ++ks) {
      bf16x8 af[4], bfr[4];
      #pragma unroll
      for (int mf = 0; mf < 4; ++mf) {
        int r = wm + mf * 16 + l15;
        int bo = r * 128 + (((ks * 4 + l4) ^ (r & 7)) * 16);
        af[mf] = __builtin_bit_cast(bf16x8, *(const u32x4*)((const char*)Asm + bo));
      }
      #pragma unroll
      for (int nf = 0; nf < 4; ++nf) {
        int r = wn + nf * 16 + l15;
        int bo = r * 128 + (((ks * 4 + l4) ^ (r & 7)) * 16);
        bfr[nf] = __builtin_bit_cast(bf16x8, *(const u32x4*)((const char*)Bsm + bo));
      }
      #pragma unroll
      for (int mf = 0; mf < 4; ++mf)
        #pragma unroll
        for (int nf = 0; nf < 4; ++nf)
          acc[mf][nf] = mfma16(af[mf], bfr[nf], acc[mf][nf]);
    }
  }
  #pragma unroll
  for (int mf = 0; mf < 4; ++mf)
    #pragma unroll
    for (int nf = 0; nf < 4; ++nf)
      #pragma unroll
      for (int reg = 0; reg < 4; ++reg) {
        int row = m0 + wm + mf * 16 + l4 * 4 + reg;
        int col = n0 + wn + nf * 16 + l15;
        float v = acc[mf][nf][reg];
        if (BF16OUT) ((u16*)Cv)[(size_t)row * N + col] = f2bf(v);
        else         ((float*)Cv)[(size_t)row * N + col] = v;
      }
}

// ---------------- sliding-window GQA flash attention (R7 structure) ----------------
__global__ __launch_bounds__(256) void attn_kernel(const u16* __restrict__ qkv,
                                                   const u16* __restrict__ vt,
                                                   u16* __restrict__ yb,
                                                   const int* __restrict__ wsz_p) {
  __shared__ __align__(16) u16 Ksm[2][64 * 128];  // [key][d], 16-chunk swizzle ^(key&15)
  __shared__ __align__(16) u16 Vsm[2][128 * 64];  // [d][key], 8-chunk swizzle ^(d&7)
  __shared__ __align__(16) u16 Psm[4 * 16 * 64];  // per-wave P 16x64, swizzled

  const int W = wsz_p[0];
  const int tid = threadIdx.x, lane = tid & 63, wid = tid >> 6;
  const int l15 = lane & 15, l4 = lane >> 4;
  const int bid = blockIdx.x;
  const int h   = bid & 15;
  const int b   = (bid >> 4) & 1;
  const int qt  = 31 - (bid >> 5);       // longest first (LPT)
  const int kvh = h >> 2;                // rep = 4
  const size_t tokb = (size_t)b * T_DIM;
  const u16* vtb = vt + ((size_t)(b * H_KV + kvh) * HD) * T_DIM;
  const int rbase = qt * 64 + wid * 16;

  auto stage = [&](int kt, int bufsel) {
    const u16* kp = qkv + (tokb + kt * 64) * NQKV + C_DIM + kvh * HD;
    #pragma unroll
    for (int i = 0; i < 4; ++i) {
      int g = wid * 4 + i;
      int row = g * 4 + (lane >> 4);
      int cs = (lane & 15) ^ (row & 15);
      gl_lds16(kp + (size_t)row * NQKV + cs * 8, (char*)Ksm[bufsel] + g * 1024);
    }
    const u16* vp = vtb + kt * 64;
    #pragma unroll
    for (int i = 0; i < 4; ++i) {
      int g = wid * 4 + i;
      int d = g * 8 + (lane >> 3);
      int cs = (lane & 7) ^ (d & 7);
      gl_lds16(vp + (size_t)d * T_DIM + cs * 8, (char*)Vsm[bufsel] + g * 1024);
    }
  };

  bf16x8 qf[4];
  {
    int r = rbase + l15;
    const u16* qp = qkv + (tokb + r) * NQKV + h * HD;
    #pragma unroll
    for (int ks = 0; ks < 4; ++ks)
      qf[ks] = __builtin_bit_cast(bf16x8, *(const u32x4*)(qp + ks * 32 + l4 * 8));
  }

  f32x4 yacc[8] = {};
  float mrow[4], lrow[4];
  #pragma unroll
  for (int rg = 0; rg < 4; ++rg) { mrow[rg] = -3.0e38f; lrow[rg] = 0.0f; }

  int smin = qt * 64 - W; if (smin < 0) smin = 0;
  const int t0 = smin >> 6;
  char* pbase = (char*)Psm + wid * 2048;

  stage(t0, 0);
  __syncthreads();
  int cur = 0;

  for (int kt = t0; kt <= qt; ++kt) {
    if (kt < qt) stage(kt + 1, cur ^ 1);

    const int slo = kt * 64;
    bool active = (slo <= rbase + 15) && ((rbase - (slo + 63)) <= W);
    if (active) {
      float Sc[4][4];
      #pragma unroll
      for (int nf = 0; nf < 4; ++nf) {
        f32x4 sa = {0.f, 0.f, 0.f, 0.f};
        int key = nf * 16 + l15;
        #pragma unroll
        for (int ks = 0; ks < 4; ++ks) {
          int bo = key * 256 + (((ks * 4 + l4) ^ (key & 15)) * 16);
          bf16x8 kf = __builtin_bit_cast(bf16x8, *(const u32x4*)((const char*)Ksm[cur] + bo));
          sa = mfma16(qf[ks], kf, sa);
        }
        #pragma unroll
        for (int rg = 0; rg < 4; ++rg) Sc[nf][rg] = sa[rg];
      }
      bool fullvalid = ((slo + 63) <= rbase) && ((rbase + 15 - slo) <= W);
      if (!fullvalid) {
        #pragma unroll
        for (int nf = 0; nf < 4; ++nf) {
          int s = slo + nf * 16 + l15;
          #pragma unroll
          for (int rg = 0; rg < 4; ++rg) {
            int r = rbase + l4 * 4 + rg;
            if (s > r || (r - s) > W) Sc[nf][rg] = -3.0e38f;
          }
        }
      }
      float tmax[4];
      #pragma unroll
      for (int rg = 0; rg < 4; ++rg) {
        float tm = fmaxf(fmaxf(Sc[0][rg], Sc[1][rg]), fmaxf(Sc[2][rg], Sc[3][rg]));
        #pragma unroll
        for (int off = 1; off < 16; off <<= 1) tm = fmaxf(tm, __shfl_xor(tm, off));
        tmax[rg] = tm;
      }
      bool small = tmax[0] <= mrow[0] + 8.f && tmax[1] <= mrow[1] + 8.f &&
                   tmax[2] <= mrow[2] + 8.f && tmax[3] <= mrow[3] + 8.f;
      if (!__all(small)) {
        f32x4 fv;
        #pragma unroll
        for (int rg = 0; rg < 4; ++rg) {
          float mnew = fmaxf(mrow[rg], tmax[rg]);
          float fm = exp2f(fmaxf(mrow[rg], -1.0e30f) - fmaxf(mnew, -1.0e30f));
          mrow[rg] = mnew;
          fv[rg] = fm;
          lrow[rg] *= fm;
        }
        #pragma unroll
        for (int nf2 = 0; nf2 < 8; ++nf2) yacc[nf2] *= fv;
      }
      float mc[4];
      #pragma unroll
      for (int rg = 0; rg < 4; ++rg) mc[rg] = fmaxf(mrow[rg], -1.0e30f);
      float rs[4] = {0.f, 0.f, 0.f, 0.f};
      #pragma unroll
      for (int nf = 0; nf < 4; ++nf)
        #pragma unroll
        for (int rg = 0; rg < 4; ++rg) {
          float pv = exp2f(Sc[nf][rg] - mc[rg]);
          unsigned int pbits = __builtin_bit_cast(unsigned int, pv);
          rs[rg] += __builtin_bit_cast(float, pbits & 0xFFFF0000u);
          int q   = l4 * 4 + rg;
          int key = nf * 16 + l15;
          int bo = q * 128 + (((key >> 3) ^ (q & 7)) * 16) + (key & 7) * 2;
          *(u16*)(pbase + bo) = (u16)(pbits >> 16);
        }
      #pragma unroll
      for (int rg = 0; rg < 4; ++rg) {
        #pragma unroll
        for (int off = 1; off < 16; off <<= 1) rs[rg] += __shfl_xor(rs[rg], off);
        lrow[rg] += rs[rg];
      }

      #pragma unroll
      for (int ks2 = 0; ks2 < 2; ++ks2) {
        int boA = l15 * 128 + (((ks2 * 4 + l4) ^ (l15 & 7)) * 16);
        bf16x8 pa = __builtin_bit_cast(bf16x8, *(const u32x4*)(pbase + boA));
        #pragma unroll
        for (int nf2 = 0; nf2 < 8; ++nf2) {
          int d = nf2 * 16 + l15;
          int boB = d * 128 + (((ks2 * 4 + l4) ^ (d & 7)) * 16);
          bf16x8 vf = __builtin_bit_cast(bf16x8, *(const u32x4*)((const char*)Vsm[cur] + boB));
          yacc[nf2] = mfma16(pa, vf, yacc[nf2]);
        }
      }
    }
    __syncthreads();
    cur ^= 1;
  }

  #pragma unroll
  for (int nf2 = 0; nf2 < 8; ++nf2)
    #pragma unroll
    for (int rg = 0; rg < 4; ++rg) {
      int r = rbase + l4 * 4 + rg;
      float v = yacc[nf2][rg] / lrow[rg];
      yb[(tokb + r) * (size_t)C_DIM + h * HD + nf2 * 16 + l15] = f2bf(v);
    }
}

// ---------------- launch ----------------
extern "C" void kernel_launch(void* const* d_in, const int* in_sizes, int n_in,
                              void* d_out, int out_size, void* d_ws, size_t ws_size,
                              hipStream_t stream) {
  const float* x    = (const float*)d_in[0];
  const float* cosb = (const float*)d_in[1];
  const float* sinb = (const float*)d_in[2];
  const float* wq   = (const float*)d_in[3];
  const float* wk   = (const float*)d_in[4];
  const float* wv   = (const float*)d_in[5];
  const float* wo   = (const float*)d_in[6];
  const int*   wsz  = (const int*)d_in[7];

  char* ws = (char*)d_ws;
  u16* xb    = (u16*)(ws);                       // 16 MB (dead after QKV GEMM)
  u16* qkvb  = (u16*)(ws + (size_t)16777216);    // 24 MB
  u16* wqkvb = (u16*)(ws + (size_t)41943040);    // 12 MB, [3072][2048]
  u16* wob   = (u16*)(ws + (size_t)54525952);    // 8 MB,  [2048][2048]
  u16* ybuf  = (u16*)(ws + (size_t)62914560);    // 16 MB
  u16* vtb   = (u16*)(ws);                       // 4 MB, reuses xb region

  prep_kernel<<<2560 + 8192, 256, 0, stream>>>(x, wq, wk, wv, wo, xb, wqkvb, wob);
  gemm256_kernel<1><<<(MTOK / 256) * (NQKV / 256), 512, 0, stream>>>(xb, wqkvb, qkvb, MTOK, NQKV, C_DIM);
  ropevt_kernel<<<256 + (MTOK * (H_Q + H_KV)) / 4, 256, 0, stream>>>(qkvb, cosb, sinb, vtb);
  attn_kernel<<<B_DIM * H_Q * (T_DIM / 64), 256, 0, stream>>>(qkvb, vtb, ybuf, wsz);
  gemm_bt_kernel<0><<<dim3(C_DIM / 128, MTOK / 128), 256, 0, stream>>>(ybuf, wob, d_out, MTOK, C_DIM, C_DIM);
}

// Round 10
// 187.302 us; speedup vs baseline: 1.0812x; 1.0812x over previous
//
#include <hip/hip_runtime.h>
#include <stdint.h>

typedef __attribute__((ext_vector_type(4))) float f32x4;
typedef __attribute__((ext_vector_type(8))) __bf16 bf16x8;
typedef __attribute__((ext_vector_type(4))) unsigned int u32x4;
typedef unsigned short u16;

#define B_DIM 2
#define T_DIM 2048
#define C_DIM 2048
#define H_Q   16
#define H_KV  4
#define HD    128
#define NQKV  3072            // 2048 q | 512 k | 512 v
#define MTOK  4096            // B*T
#define RMS_EPS 1.1920928955078125e-07f
// 1/sqrt(128) * log2(e), folded into q's rms scale so S comes out in exp2 domain
#define Q_SCALE 0.12751749f

__device__ __forceinline__ u16 f2bf(float f) {
  union { float f; unsigned int u; } v; v.f = f;
  unsigned int r = v.u + 0x7FFFu + ((v.u >> 16) & 1u);   // RNE
  return (u16)(r >> 16);
}
__device__ __forceinline__ float bf2f(u16 h) {
  union { unsigned int u; float f; } v; v.u = ((unsigned int)h) << 16;
  return v.f;
}
__device__ __forceinline__ f32x4 mfma16(bf16x8 a, bf16x8 b, f32x4 c) {
  return __builtin_amdgcn_mfma_f32_16x16x32_bf16(a, b, c, 0, 0, 0);
}
// async global->LDS, 16B per lane; lds base must be wave-uniform (HW: base + lane*16)
__device__ __forceinline__ void gl_lds16(const void* g, void* l) {
  __builtin_amdgcn_global_load_lds(
      (const __attribute__((address_space(1))) unsigned int*)g,
      (__attribute__((address_space(3))) unsigned int*)l, 16, 0, 0);
}

// ---------------- prep: weight transposes (blocks 0..2559) + x cast (rest) ----------------
__global__ __launch_bounds__(256) void prep_kernel(const float* __restrict__ x,
                                                   const float* __restrict__ wq,
                                                   const float* __restrict__ wk,
                                                   const float* __restrict__ wv,
                                                   const float* __restrict__ wo,
                                                   u16* __restrict__ xb,
                                                   u16* __restrict__ wqkvb,
                                                   u16* __restrict__ wob) {
  __shared__ float tile[64][65];
  int bid = blockIdx.x, t = threadIdx.x;
  if (bid < 2560) {                       // transpose+cast fp32 [K][N] -> bf16 [N][2048]
    int nb = bid % 80, kb = bid / 80;
    const float* src; u16* dst; int srcN, nloc;
    if (nb < 32)      { src = wq; srcN = 2048; nloc = nb;      dst = wqkvb; }
    else if (nb < 40) { src = wk; srcN = 512;  nloc = nb - 32; dst = wqkvb + (size_t)2048 * 2048; }
    else if (nb < 48) { src = wv; srcN = 512;  nloc = nb - 40; dst = wqkvb + (size_t)2560 * 2048; }
    else              { src = wo; srcN = 2048; nloc = nb - 48; dst = wob; }
    int n0 = nloc * 64, k0 = kb * 64;
    #pragma unroll
    for (int idx = t; idx < 4096; idx += 256) {
      int r = idx >> 6, c = idx & 63;
      tile[r][c] = src[(size_t)(k0 + r) * srcN + n0 + c];
    }
    __syncthreads();
    #pragma unroll
    for (int idx = t; idx < 4096; idx += 256) {
      int r = idx >> 6, c = idx & 63;
      dst[(size_t)(n0 + r) * 2048 + k0 + c] = f2bf(tile[c][r]);
    }
  } else {                                // cast x
    int i = ((bid - 2560) * 256 + t) * 4;
    if (i >= MTOK * C_DIM) return;
    float4 v = *(const float4*)(x + i);
    u16 o0 = f2bf(v.x), o1 = f2bf(v.y), o2 = f2bf(v.z), o3 = f2bf(v.w);
    unsigned int lo = (unsigned int)o0 | ((unsigned int)o1 << 16);
    unsigned int hi = (unsigned int)o2 | ((unsigned int)o3 << 16);
    *(uint2*)(xb + i) = make_uint2(lo, hi);
  }
}

// ---------------- rope+rms (in place on q,k) + V^T precompute, one dispatch ----------------
// q heads additionally scaled by Q_SCALE so attention scores land in exp2 domain.
__global__ __launch_bounds__(256) void ropevt_kernel(u16* __restrict__ qkv,
                                                     const float* __restrict__ cosb,
                                                     const float* __restrict__ sinb,
                                                     u16* __restrict__ vt) {
  __shared__ __align__(16) u16 tile[64][136];
  int bid = blockIdx.x, tid = threadIdx.x;
  if (bid < 256) {                        // vtrans: qkv v-section -> vt[b][kvh][d][T]
    int tt0 = (bid & 31) * 64;
    int kvh = (bid >> 5) & 3;
    int b   = bid >> 7;
    const u16* vp = qkv + ((size_t)b * T_DIM + tt0) * NQKV + C_DIM + H_KV * HD + kvh * HD;
    #pragma unroll
    for (int i = 0; i < 4; ++i) {
      int cid = tid + i * 256;
      int r = cid >> 4, c = cid & 15;
      u32x4 v = *(const u32x4*)(vp + (size_t)r * NQKV + c * 8);
      *(u32x4*)&tile[r][c * 8] = v;
    }
    __syncthreads();
    u16* op = vt + ((size_t)(b * H_KV + kvh) * HD) * T_DIM + tt0;
    #pragma unroll
    for (int i = 0; i < 4; ++i) {
      int cid = tid + i * 256;
      int d = cid >> 3, tc = cid & 7;
      u16 vals[8];
      #pragma unroll
      for (int j = 0; j < 8; ++j) vals[j] = tile[tc * 8 + j][d];
      u32x4 w;
      w.x = (unsigned int)vals[0] | ((unsigned int)vals[1] << 16);
      w.y = (unsigned int)vals[2] | ((unsigned int)vals[3] << 16);
      w.z = (unsigned int)vals[4] | ((unsigned int)vals[5] << 16);
      w.w = (unsigned int)vals[6] | ((unsigned int)vals[7] << 16);
      *(u32x4*)(op + (size_t)d * T_DIM + tc * 8) = w;
    }
  } else {                                // rope+rms: one wave per (token, head)
    int gw = ((bid - 256) * 256 + tid) >> 6;
    int lane = tid & 63;
    int hh = gw % (H_Q + H_KV);
    int tok = gw / (H_Q + H_KV);
    int t = tok & (T_DIM - 1);
    bool isq = (hh < H_Q);
    int base = isq ? hh * HD : (C_DIM + (hh - H_Q) * HD);
    u16* p = qkv + (size_t)tok * NQKV + base;
    float x1 = bf2f(p[lane]);
    float x2 = bf2f(p[lane + 64]);
    float c = cosb[t * 64 + lane];
    float s = sinb[t * 64 + lane];
    float o1 =  x1 * c + x2 * s;
    float o2 = -x1 * s + x2 * c;
    float ss = o1 * o1 + o2 * o2;
    #pragma unroll
    for (int off = 1; off < 64; off <<= 1) ss += __shfl_xor(ss, off);
    float r = rsqrtf(ss * (1.0f / 128.0f) + RMS_EPS);
    if (isq) r *= Q_SCALE;
    p[lane]      = f2bf(o1 * r);
    p[lane + 64] = f2bf(o2 * r);
  }
}

// ---------------- bf16 GEMM: C[M][N] = A[M][K] * Bt[N][K]^T ----------------
// 128x128 tile, BK=64, 4 waves. global_load_lds staging, pre-swizzled source.
// (256^2 8-phase tried R8/R9: both 670 TF vs this structure's 785 TF at these
// shapes -- 75% grid fill + 1 block/CU loses more than the schedule gains.)
template<int BF16OUT>
__global__ __launch_bounds__(256) void gemm_bt_kernel(const u16* __restrict__ A,
                                                      const u16* __restrict__ Bt,
                                                      void* __restrict__ Cv,
                                                      int M, int N, int K) {
  __shared__ __align__(16) u16 Asm[128 * 64];
  __shared__ __align__(16) u16 Bsm[128 * 64];
  const int tid = threadIdx.x;
  const int lane = tid & 63;
  const int wid = tid >> 6;
  const int m0 = blockIdx.y * 128, n0 = blockIdx.x * 128;
  const int wm = (wid >> 1) * 64, wn = (wid & 1) * 64;
  const int l15 = lane & 15, l4 = lane >> 4;
  const int csrc = (lane & 7) ^ (lane >> 3);      // pre-swizzled source chunk
  f32x4 acc[4][4] = {};

  for (int k0 = 0; k0 < K; k0 += 64) {
    __syncthreads();
    #pragma unroll
    for (int i = 0; i < 4; ++i) {
      int g = wid * 4 + i;
      int row = g * 8 + (lane >> 3);
      gl_lds16(A  + (size_t)(m0 + row) * K + k0 + csrc * 8, (char*)Asm + g * 1024);
      gl_lds16(Bt + (size_t)(n0 + row) * K + k0 + csrc * 8, (char*)Bsm + g * 1024);
    }
    __syncthreads();
    #pragma unroll
    for (int ks = 0; ks < 2; ++ks) {
      bf16x8 af[4], bfr[4];
      #pragma unroll
      for (int mf = 0; mf < 4; ++mf) {
        int r = wm + mf * 16 + l15;
        int bo = r * 128 + (((ks * 4 + l4) ^ (r & 7)) * 16);
        af[mf] = __builtin_bit_cast(bf16x8, *(const u32x4*)((const char*)Asm + bo));
      }
      #pragma unroll
      for (int nf = 0; nf < 4; ++nf) {
        int r = wn + nf * 16 + l15;
        int bo = r * 128 + (((ks * 4 + l4) ^ (r & 7)) * 16);
        bfr[nf] = __builtin_bit_cast(bf16x8, *(const u32x4*)((const char*)Bsm + bo));
      }
      #pragma unroll
      for (int mf = 0; mf < 4; ++mf)
        #pragma unroll
        for (int nf = 0; nf < 4; ++nf)
          acc[mf][nf] = mfma16(af[mf], bfr[nf], acc[mf][nf]);
    }
  }
  #pragma unroll
  for (int mf = 0; mf < 4; ++mf)
    #pragma unroll
    for (int nf = 0; nf < 4; ++nf)
      #pragma unroll
      for (int reg = 0; reg < 4; ++reg) {
        int row = m0 + wm + mf * 16 + l4 * 4 + reg;
        int col = n0 + wn + nf * 16 + l15;
        float v = acc[mf][nf][reg];
        if (BF16OUT) ((u16*)Cv)[(size_t)row * N + col] = f2bf(v);
        else         ((float*)Cv)[(size_t)row * N + col] = v;
      }
}

// ---------------- sliding-window GQA flash attention ----------------
// R6 skeleton (dbuf prefetch, gl_lds staging, LPT) + R7 softmax trims +
// NEW: softmax denominator via ones-column MFMA (ylsum = P @ 1) -- deletes the
// 16-shfl row-sum reduction; ylsum auto-rescales with the deferred-max factor.
__global__ __launch_bounds__(256, 4) void attn_kernel(const u16* __restrict__ qkv,
                                                      const u16* __restrict__ vt,
                                                      u16* __restrict__ yb,
                                                      const int* __restrict__ wsz_p) {
  __shared__ __align__(16) u16 Ksm[2][64 * 128];  // [key][d], 16-chunk swizzle ^(key&15)
  __shared__ __align__(16) u16 Vsm[2][128 * 64];  // [d][key], 8-chunk swizzle ^(d&7)
  __shared__ __align__(16) u16 Psm[4 * 16 * 64];  // per-wave P 16x64, swizzled

  const int W = wsz_p[0];
  const int tid = threadIdx.x, lane = tid & 63, wid = tid >> 6;
  const int l15 = lane & 15, l4 = lane >> 4;
  const int bid = blockIdx.x;
  const int h   = bid & 15;
  const int b   = (bid >> 4) & 1;
  const int qt  = 31 - (bid >> 5);       // longest first (LPT)
  const int kvh = h >> 2;                // rep = 4
  const size_t tokb = (size_t)b * T_DIM;
  const u16* vtb = vt + ((size_t)(b * H_KV + kvh) * HD) * T_DIM;
  const int rbase = qt * 64 + wid * 16;

  auto stage = [&](int kt, int bufsel) {
    const u16* kp = qkv + (tokb + kt * 64) * NQKV + C_DIM + kvh * HD;
    #pragma unroll
    for (int i = 0; i < 4; ++i) {
      int g = wid * 4 + i;
      int row = g * 4 + (lane >> 4);
      int cs = (lane & 15) ^ (row & 15);
      gl_lds16(kp + (size_t)row * NQKV + cs * 8, (char*)Ksm[bufsel] + g * 1024);
    }
    const u16* vp = vtb + kt * 64;
    #pragma unroll
    for (int i = 0; i < 4; ++i) {
      int g = wid * 4 + i;
      int d = g * 8 + (lane >> 3);
      int cs = (lane & 7) ^ (d & 7);
      gl_lds16(vp + (size_t)d * T_DIM + cs * 8, (char*)Vsm[bufsel] + g * 1024);
    }
  };

  bf16x8 qf[4];
  {
    int r = rbase + l15;
    const u16* qp = qkv + (tokb + r) * NQKV + h * HD;
    #pragma unroll
    for (int ks = 0; ks < 4; ++ks)
      qf[ks] = __builtin_bit_cast(bf16x8, *(const u32x4*)(qp + ks * 32 + l4 * 8));
  }

  const u32x4 onesu = {0x3F803F80u, 0x3F803F80u, 0x3F803F80u, 0x3F803F80u};
  const bf16x8 onesf = __builtin_bit_cast(bf16x8, onesu);   // 8 x bf16(1.0)

  f32x4 yacc[8] = {};
  f32x4 ylsum = {0.f, 0.f, 0.f, 0.f};    // softmax denominator, via P @ ones
  float mrow[4];
  #pragma unroll
  for (int rg = 0; rg < 4; ++rg) mrow[rg] = -3.0e38f;

  int smin = qt * 64 - W; if (smin < 0) smin = 0;
  const int t0 = smin >> 6;
  char* pbase = (char*)Psm + wid * 2048;

  stage(t0, 0);
  __syncthreads();
  int cur = 0;

  for (int kt = t0; kt <= qt; ++kt) {
    if (kt < qt) stage(kt + 1, cur ^ 1);

    const int slo = kt * 64;
    bool active = (slo <= rbase + 15) && ((rbase - (slo + 63)) <= W);
    if (active) {
      // S = Q K^T (exp2 domain; Q pre-scaled)
      float Sc[4][4];
      #pragma unroll
      for (int nf = 0; nf < 4; ++nf) {
        f32x4 sa = {0.f, 0.f, 0.f, 0.f};
        int key = nf * 16 + l15;
        #pragma unroll
        for (int ks = 0; ks < 4; ++ks) {
          int bo = key * 256 + (((ks * 4 + l4) ^ (key & 15)) * 16);
          bf16x8 kf = __builtin_bit_cast(bf16x8, *(const u32x4*)((const char*)Ksm[cur] + bo));
          sa = mfma16(qf[ks], kf, sa);
        }
        #pragma unroll
        for (int rg = 0; rg < 4; ++rg) Sc[nf][rg] = sa[rg];
      }
      // mask only when tile not fully valid for this wave
      bool fullvalid = ((slo + 63) <= rbase) && ((rbase + 15 - slo) <= W);
      if (!fullvalid) {
        #pragma unroll
        for (int nf = 0; nf < 4; ++nf) {
          int s = slo + nf * 16 + l15;
          #pragma unroll
          for (int rg = 0; rg < 4; ++rg) {
            int r = rbase + l4 * 4 + rg;
            if (s > r || (r - s) > W) Sc[nf][rg] = -3.0e38f;
          }
        }
      }
      // tile max per row (wave-reduced over the 16 key-lanes)
      float tmax[4];
      #pragma unroll
      for (int rg = 0; rg < 4; ++rg) {
        float tm = fmaxf(fmaxf(Sc[0][rg], Sc[1][rg]), fmaxf(Sc[2][rg], Sc[3][rg]));
        #pragma unroll
        for (int off = 1; off < 16; off <<= 1) tm = fmaxf(tm, __shfl_xor(tm, off));
        tmax[rg] = tm;
      }
      // T13 defer-rescale: skip when no row's max grew by >8 (P bounded by 2^8)
      bool small = tmax[0] <= mrow[0] + 8.f && tmax[1] <= mrow[1] + 8.f &&
                   tmax[2] <= mrow[2] + 8.f && tmax[3] <= mrow[3] + 8.f;
      if (!__all(small)) {
        f32x4 fv;
        #pragma unroll
        for (int rg = 0; rg < 4; ++rg) {
          float mnew = fmaxf(mrow[rg], tmax[rg]);
          fv[rg] = exp2f(fmaxf(mrow[rg], -1.0e30f) - fmaxf(mnew, -1.0e30f));
          mrow[rg] = mnew;
        }
        #pragma unroll
        for (int nf2 = 0; nf2 < 8; ++nf2) yacc[nf2] *= fv;
        ylsum *= fv;
      }
      float mc[4];
      #pragma unroll
      for (int rg = 0; rg < 4; ++rg) mc[rg] = fmaxf(mrow[rg], -1.0e30f);
      // P = exp2(S - m), truncation-cast to bf16 -> wave-private LDS
      #pragma unroll
      for (int nf = 0; nf < 4; ++nf)
        #pragma unroll
        for (int rg = 0; rg < 4; ++rg) {
          float pv = exp2f(Sc[nf][rg] - mc[rg]);
          unsigned int pbits = __builtin_bit_cast(unsigned int, pv);
          int q   = l4 * 4 + rg;
          int key = nf * 16 + l15;
          int bo = q * 128 + (((key >> 3) ^ (q & 7)) * 16) + (key & 7) * 2;
          *(u16*)(pbase + bo) = (u16)(pbits >> 16);
        }

      // PV: y(16x128) += P(16x64) @ V(64x128);  denominator: ylsum += P @ 1
      #pragma unroll
      for (int ks2 = 0; ks2 < 2; ++ks2) {
        int boA = l15 * 128 + (((ks2 * 4 + l4) ^ (l15 & 7)) * 16);
        bf16x8 pa = __builtin_bit_cast(bf16x8, *(const u32x4*)(pbase + boA));
        ylsum = mfma16(pa, onesf, ylsum);
        #pragma unroll
        for (int nf2 = 0; nf2 < 8; ++nf2) {
          int d = nf2 * 16 + l15;
          int boB = d * 128 + (((ks2 * 4 + l4) ^ (d & 7)) * 16);
          bf16x8 vf = __builtin_bit_cast(bf16x8, *(const u32x4*)((const char*)Vsm[cur] + boB));
          yacc[nf2] = mfma16(pa, vf, yacc[nf2]);
        }
      }
    }
    __syncthreads();
    cur ^= 1;
  }

  // normalize + write y (bf16)
  #pragma unroll
  for (int nf2 = 0; nf2 < 8; ++nf2)
    #pragma unroll
    for (int rg = 0; rg < 4; ++rg) {
      int r = rbase + l4 * 4 + rg;
      float v = yacc[nf2][rg] / ylsum[rg];
      yb[(tokb + r) * (size_t)C_DIM + h * HD + nf2 * 16 + l15] = f2bf(v);
    }
}

// ---------------- launch ----------------
extern "C" void kernel_launch(void* const* d_in, const int* in_sizes, int n_in,
                              void* d_out, int out_size, void* d_ws, size_t ws_size,
                              hipStream_t stream) {
  const float* x    = (const float*)d_in[0];
  const float* cosb = (const float*)d_in[1];
  const float* sinb = (const float*)d_in[2];
  const float* wq   = (const float*)d_in[3];
  const float* wk   = (const float*)d_in[4];
  const float* wv   = (const float*)d_in[5];
  const float* wo   = (const float*)d_in[6];
  const int*   wsz  = (const int*)d_in[7];

  char* ws = (char*)d_ws;
  u16* xb    = (u16*)(ws);                       // 16 MB (dead after QKV GEMM)
  u16* qkvb  = (u16*)(ws + (size_t)16777216);    // 24 MB
  u16* wqkvb = (u16*)(ws + (size_t)41943040);    // 12 MB, [3072][2048]
  u16* wob   = (u16*)(ws + (size_t)54525952);    // 8 MB,  [2048][2048]
  u16* ybuf  = (u16*)(ws + (size_t)62914560);    // 16 MB
  u16* vtb   = (u16*)(ws);                       // 4 MB, reuses xb region

  prep_kernel<<<2560 + 8192, 256, 0, stream>>>(x, wq, wk, wv, wo, xb, wqkvb, wob);
  gemm_bt_kernel<1><<<dim3(NQKV / 128, MTOK / 128), 256, 0, stream>>>(xb, wqkvb, qkvb, MTOK, NQKV, C_DIM);
  ropevt_kernel<<<256 + (MTOK * (H_Q + H_KV)) / 4, 256, 0, stream>>>(qkvb, cosb, sinb, vtb);
  attn_kernel<<<B_DIM * H_Q * (T_DIM / 64), 256, 0, stream>>>(qkvb, vtb, ybuf, wsz);
  gemm_bt_kernel<0><<<dim3(C_DIM / 128, MTOK / 128), 256, 0, stream>>>(ybuf, wob, d_out, MTOK, C_DIM, C_DIM);
}